// Round 4
// baseline (350.635 us; speedup 1.0000x reference)
//
#include <hip/hip_runtime.h>
#include <math.h>

#define H 256
#define BATCH 128
#define CDIM 10
#define HH (H*H)      // 65536
#define NCHEB 8       // PS-Chebyshev degree

typedef unsigned short u16;
typedef unsigned int u32;
typedef __attribute__((ext_vector_type(8))) short bf16x8;
typedef __attribute__((ext_vector_type(8))) unsigned short u16x8;
typedef __attribute__((ext_vector_type(4))) float f32x4;

__device__ __forceinline__ u16 f2bf(float f){
    u32 u = __float_as_uint(f);
    u = (u + 0x7FFFu + ((u >> 16) & 1u)) >> 16;   // RNE
    return (u16)u;
}
__device__ __forceinline__ float bf2f(u16 h){
    return __uint_as_float(((u32)h) << 16);
}

// async global->LDS, 16B per lane. lds must be wave-uniform base; g is per-lane.
__device__ __forceinline__ void async16(void* lds, const void* g){
    __builtin_amdgcn_global_load_lds(
        (const __attribute__((address_space(1))) u32*)g,
        (__attribute__((address_space(3))) u32*)lds, 16, 0, 0);
}

// ---------------- prep: t = (X - c I)/h  (bf16)
__global__ void prep_kernel(const float4* __restrict__ X4, ushort4* __restrict__ t4,
                            float cc, float hinv)
{
    const int total4 = BATCH * HH / 4;
    for (int idx = blockIdx.x * blockDim.x + threadIdx.x; idx < total4;
         idx += gridDim.x * blockDim.x) {
        int ij4 = idx & (HH/4 - 1);
        int i = ij4 >> 6;
        int jb = (ij4 & 63) << 2;
        float4 x = X4[idx];
        float d0 = (i == jb+0) ? 1.0f : 0.0f;
        float d1 = (i == jb+1) ? 1.0f : 0.0f;
        float d2 = (i == jb+2) ? 1.0f : 0.0f;
        float d3 = (i == jb+3) ? 1.0f : 0.0f;
        ushort4 to;
        to.x = f2bf((x.x - cc*d0) * hinv);
        to.y = f2bf((x.y - cc*d1) * hinv);
        to.z = f2bf((x.z - cc*d2) * hinv);
        to.w = f2bf((x.w - cc*d3) * hinv);
        t4[idx] = to;
    }
}

// ---------------- bf16 MFMA batched mm, MODE-specialized epilogues.
// All operand matrices are SYMMETRIC 256x256 bf16 -> B-fragments load like A-fragments.
// MODE 0: Out(bf16) = sc*(A@B) + (hasPrev? ps*Prev) + adiag*I
// MODE 1: v4 = sc*(A@B) + ps*Prev (Prev=T2); write Out=T4(bf16),
//         OutU = k5*t + k6*T2 + k7*T3 + k8*v4, OutC = q0*I + q1*t + q2*T2 + q3*T3 + q4*v4
//         (OutC aliases the T2 buffer: per-thread RMW at same element; no cross-block T2 reads)
// MODE 2: feats v = sc*(A@B) + ps*Prev (Prev=C0); write Out=feats(bf16) AND fused
//         out-partials: outpart[bz][tile][c] = sum ws_c * v over this block's tile
// MODE 3: Out(fp32) = sc*(A@B)   (for P = Ws@center)
template<int MODE>
__global__ __launch_bounds__(256)
void mm_bf16(const u16* __restrict__ A, const u16* __restrict__ B,
             const u16* __restrict__ Pv, void* __restrict__ Out,
             u16* __restrict__ OutU, u16* __restrict__ OutC,
             const u16* __restrict__ E1, const u16* __restrict__ E3,
             const u16* __restrict__ Wsb, float* __restrict__ outpart,
             int bstride, int hasPrev, float sc, float ps, float adiag,
             float k5, float k6, float k7, float k8,
             float q0, float q1, float q2, float q3, float q4)
{
    __shared__ u16 Als[128*64];   // 1024 slots of 16B, slot=(row<<3)|s, source-XOR-swizzled
    __shared__ u16 Bls[128*64];

    // XCD-chunked remap: group consecutive linear block ids per XCD
    const int gx = gridDim.x, gy = gridDim.y;
    const int nwg = gx * gy * gridDim.z;
    int lid = blockIdx.x + gx * (blockIdx.y + gy * blockIdx.z);
    int chunk = nwg >> 3;
    int nid = (lid & 7) * chunk + (lid >> 3);
    int bx = nid % gx; int rr = nid / gx; int by = rr % gy; int bz = rr / gy;

    const u16* Ab = A + (size_t)bz * HH;
    const u16* Bb = B + (size_t)bz * HH * bstride;

    const int i0 = bx * 128, j0 = by * 128;
    const int tid = threadIdx.x;
    const int lane = tid & 63;
    const int w = tid >> 6, wr = w >> 1, wc = w & 1;

    f32x4 acc[4][4];
    #pragma unroll
    for (int m = 0; m < 4; m++)
        #pragma unroll
        for (int n = 0; n < 4; n++)
            acc[m][n] = (f32x4)(0.0f);

    for (int k0 = 0; k0 < H; k0 += 64) {
        #pragma unroll
        for (int is = 0; is < 4; is++) {
            int slot = is * 256 + w * 64 + lane;
            int row = slot >> 3, s = slot & 7;
            int gs = s ^ (row & 7);
            async16(&Als[(size_t)(is * 256 + w * 64) * 8],
                    (const char*)Ab + ((size_t)(i0 + row) * H + k0) * 2 + gs * 16);
            async16(&Bls[(size_t)(is * 256 + w * 64) * 8],
                    (const char*)Bb + ((size_t)(j0 + row) * H + k0) * 2 + gs * 16);
        }
        __syncthreads();

        #pragma unroll
        for (int kk = 0; kk < 2; kk++) {
            bf16x8 av[4], bv[4];
            int gsl = kk * 4 + (lane >> 4);
            #pragma unroll
            for (int m = 0; m < 4; m++) {
                int row = wr * 64 + m * 16 + (lane & 15);
                av[m] = *reinterpret_cast<const bf16x8*>(
                    (const char*)Als + row * 128 + ((gsl ^ (row & 7)) * 16));
            }
            #pragma unroll
            for (int n = 0; n < 4; n++) {
                int row = wc * 64 + n * 16 + (lane & 15);  // col of B == row (symmetric)
                bv[n] = *reinterpret_cast<const bf16x8*>(
                    (const char*)Bls + row * 128 + ((gsl ^ (row & 7)) * 16));
            }
            #pragma unroll
            for (int m = 0; m < 4; m++)
                #pragma unroll
                for (int n = 0; n < 4; n++)
                    acc[m][n] = __builtin_amdgcn_mfma_f32_16x16x32_bf16(
                        av[m], bv[n], acc[m][n], 0, 0, 0);
        }
        __syncthreads();
    }

    // epilogue: C/D layout col=lane&15, row=(lane>>4)*4+reg (m89/m91 verified)
    const int rl = (lane >> 4) * 4, cl = lane & 15;
    float outacc[CDIM];
    if (MODE == 2) {
        #pragma unroll
        for (int c = 0; c < CDIM; c++) outacc[c] = 0.0f;
    }

    #pragma unroll
    for (int m = 0; m < 4; m++) {
        #pragma unroll
        for (int n = 0; n < 4; n++) {
            int gcol = j0 + wc * 64 + n * 16 + cl;
            #pragma unroll
            for (int r = 0; r < 4; r++) {
                int grow = i0 + wr * 64 + m * 16 + rl + r;
                size_t pos = (size_t)grow * H + gcol;
                size_t bpos = (size_t)bz * HH + pos;
                float prevv = 0.0f;
                if (MODE == 1 || hasPrev) prevv = bf2f(Pv[bpos]);
                float v = sc * acc[m][n][r] + ps * prevv;
                if (grow == gcol) v += adiag;

                if (MODE == 0) {
                    ((u16*)Out)[bpos] = f2bf(v);
                } else if (MODE == 1) {
                    float e1 = bf2f(E1[bpos]);
                    float e3 = bf2f(E3[bpos]);
                    float dg = (grow == gcol) ? 1.0f : 0.0f;
                    ((u16*)Out)[bpos] = f2bf(v);  // T4
                    OutU[bpos] = f2bf(k5 * e1 + k6 * prevv + k7 * e3 + k8 * v);
                    OutC[bpos] = f2bf(q0 * dg + q1 * e1 + q2 * prevv + q3 * e3 + q4 * v);
                } else if (MODE == 2) {
                    ((u16*)Out)[bpos] = f2bf(v);  // feats
                    #pragma unroll
                    for (int c = 0; c < CDIM; c++)
                        outacc[c] = fmaf(bf2f(Wsb[(size_t)c * HH + pos]), v, outacc[c]);
                } else { // MODE 3
                    ((float*)Out)[bpos] = v;
                }
            }
        }
    }

    if (MODE == 2) {
        __syncthreads();
        float* redls = (float*)Als;
        #pragma unroll
        for (int c = 0; c < CDIM; c++) {
            float rv = outacc[c];
            #pragma unroll
            for (int off = 32; off >= 1; off >>= 1) rv += __shfl_down(rv, off, 64);
            if (lane == 0) redls[w * CDIM + c] = rv;
        }
        __syncthreads();
        if (tid < CDIM) {
            float s = redls[0*CDIM + tid] + redls[1*CDIM + tid]
                    + redls[2*CDIM + tid] + redls[3*CDIM + tid];
            outpart[((size_t)bz * 4 + (by * 2 + bx)) * CDIM + tid] = s;
        }
    }
}

// ---------------- Wsym bf16 = 0.5 (W + W^T)
__global__ void symw_kernel(const float* __restrict__ W, u16* __restrict__ Wsb)
{
    const int total = CDIM * HH;
    for (int idx = blockIdx.x * blockDim.x + threadIdx.x; idx < total;
         idx += gridDim.x * blockDim.x) {
        int c  = idx >> 16;
        int ij = idx & (HH-1);
        int i = ij >> 8, j = ij & (H-1);
        Wsb[idx] = f2bf(0.5f * (W[idx] + W[(c << 16) + (j << 8) + i]));
    }
}

// ---------------- out[b,c] = sum over 4 tiles of fused partials
__global__ void out_reduce_kernel(const float* __restrict__ outpart, float* __restrict__ out)
{
    int idx = blockIdx.x * blockDim.x + threadIdx.x;
    if (idx < BATCH * CDIM) {
        int b = idx / CDIM, c = idx % CDIM;
        float v = 0.0f;
        #pragma unroll
        for (int t = 0; t < 4; t++) v += outpart[((size_t)b * 4 + t) * CDIM + c];
        out[idx] = v;
    }
}

// ---------------- center stage 1: partial sums over 16 batches each
__global__ __launch_bounds__(256)
void cpart_kernel(const u16* __restrict__ feats, float* __restrict__ cpart)
{
    int idx = blockIdx.x * 256 + threadIdx.x;    // ushort8 position, 0..8191
    int chunk = blockIdx.y;                      // 0..7
    const u16x8* f8 = (const u16x8*)feats;
    float s[8];
    #pragma unroll
    for (int l = 0; l < 8; l++) s[l] = 0.0f;
    for (int b = 0; b < 16; b++) {
        u16x8 v = f8[(size_t)(chunk*16 + b) * (HH/8) + idx];
        #pragma unroll
        for (int l = 0; l < 8; l++) s[l] += bf2f(v[l]);
    }
    float* dst = cpart + (size_t)chunk * HH + (size_t)idx * 8;
    *reinterpret_cast<float4*>(dst)     = make_float4(s[0], s[1], s[2], s[3]);
    *reinterpret_cast<float4*>(dst + 4) = make_float4(s[4], s[5], s[6], s[7]);
}

// ---------------- center stage 2: sum 8 chunks, /128, write bf16
__global__ __launch_bounds__(256)
void cfinal_kernel(const float* __restrict__ cpart, u16* __restrict__ centerb)
{
    int idx = blockIdx.x * 256 + threadIdx.x;    // 0..8191
    float s[8];
    #pragma unroll
    for (int l = 0; l < 8; l++) s[l] = 0.0f;
    #pragma unroll
    for (int ch = 0; ch < 8; ch++) {
        const float* src = cpart + (size_t)ch * HH + (size_t)idx * 8;
        float4 p0 = *reinterpret_cast<const float4*>(src);
        float4 p1 = *reinterpret_cast<const float4*>(src + 4);
        s[0]+=p0.x; s[1]+=p0.y; s[2]+=p0.z; s[3]+=p0.w;
        s[4]+=p1.x; s[5]+=p1.y; s[6]+=p1.z; s[7]+=p1.w;
    }
    u16x8 o;
    #pragma unroll
    for (int l = 0; l < 8; l++) o[l] = f2bf(s[l] * (1.0f / BATCH));
    ((u16x8*)centerb)[idx] = o;
}

// ---------------- g partial: grid (CDIM, 8); 32 rows per block
__global__ __launch_bounds__(256)
void g_kernel(const float* __restrict__ P, float* __restrict__ gpart)
{
    int c = blockIdx.x, r0 = blockIdx.y * 32;
    const float* Pc = P + (size_t)c * HH;
    float acc = 0.0f;
    for (int idx = threadIdx.x; idx < 32 * H; idx += 256) {
        int i = r0 + (idx >> 8), j = idx & (H-1);
        acc += Pc[i * H + j] * Pc[j * H + i];
    }
    __shared__ float red[4];
    int lane = threadIdx.x & 63, wv = threadIdx.x >> 6;
    #pragma unroll
    for (int off = 32; off >= 1; off >>= 1) acc += __shfl_down(acc, off, 64);
    if (lane == 0) red[wv] = acc;
    __syncthreads();
    if (threadIdx.x == 0)
        gpart[c * 8 + blockIdx.y] = red[0] + red[1] + red[2] + red[3];
}

__global__ void gmean_kernel(const float* __restrict__ gpart, float* __restrict__ out)
{
    if (threadIdx.x == 0) {
        float s = 0.0f;
        for (int i = 0; i < CDIM * 8; i++) s += gpart[i];
        out[BATCH*CDIM] = s * (1.0f / CDIM);
    }
}

extern "C" void kernel_launch(void* const* d_in, const int* in_sizes, int n_in,
                              void* d_out, int out_size, void* d_ws, size_t ws_size,
                              hipStream_t stream)
{
    const float* X = (const float*)d_in[0];   // [128,256,256]
    const float* W = (const float*)d_in[1];   // [10,256,256]
    float* out = (float*)d_out;               // 1281 floats

    char* wp = (char*)d_ws;
    u16* tb  = (u16*)wp;  wp += (size_t)BATCH * HH * 2;   // t -> feats (final mm out)
    u16* T2  = (u16*)wp;  wp += (size_t)BATCH * HH * 2;   // T2 -> C0 (in-place, MODE1)
    u16* T3  = (u16*)wp;  wp += (size_t)BATCH * HH * 2;
    u16* T4  = (u16*)wp;  wp += (size_t)BATCH * HH * 2;
    u16* U   = (u16*)wp;  wp += (size_t)BATCH * HH * 2;
    u16*   Wsb    = (u16*)wp;    wp += (size_t)CDIM * HH * 2;
    u16*   centerb= (u16*)wp;    wp += (size_t)HH * 2;
    float* P      = (float*)wp;  wp += (size_t)CDIM * HH * 4;
    float* cpart  = (float*)wp;  wp += (size_t)8 * HH * 4;
    float* outpart= (float*)wp;  wp += (size_t)BATCH * 4 * CDIM * 4;
    float* gpart  = (float*)wp;

    // Chebyshev coefficients of log(x) on [lo, hi] (closed form)
    const double lo = 0.98, hi = 5.80;
    const double cc = 0.5 * (hi + lo), hh = 0.5 * (hi - lo);
    const double alpha = hh / cc;
    const double beta = (sqrt(1.0 - alpha*alpha) - 1.0) / alpha;
    double a[NCHEB + 1];
    a[0] = log(cc) - log(1.0 + beta*beta);
    double bp = 1.0;
    for (int k = 1; k <= NCHEB; k++) { bp *= beta; a[k] = -2.0 * bp / k; }

    prep_kernel<<<1024, 256, 0, stream>>>((const float4*)X, (ushort4*)tb,
                                          (float)cc, (float)(1.0 / hh));
    symw_kernel<<<64, 256, 0, stream>>>(W, Wsb);

    dim3 mmgrid(2, 2, BATCH);
    // T2 = 2 t@t - I
    mm_bf16<0><<<mmgrid, 256, 0, stream>>>(tb, tb, nullptr, T2, nullptr, nullptr,
        nullptr, nullptr, nullptr, nullptr, 1, 0, 2.0f, 0.0f, -1.0f,
        0,0,0,0, 0,0,0,0,0);
    // T3 = 2 t@T2 - t
    mm_bf16<0><<<mmgrid, 256, 0, stream>>>(tb, T2, tb, T3, nullptr, nullptr,
        nullptr, nullptr, nullptr, nullptr, 1, 1, 2.0f, -1.0f, 0.0f,
        0,0,0,0, 0,0,0,0,0);
    // T4 = 2 t@T3 - T2 ; U = a5 t + a6 T2 + a7 T3 + a8 T4 ;
    // C0 = (a0-a8) I + (a1-a7) t + (a2-a6) T2 + (a3-a5) T3 + a4 T4  (over T2 buffer)
    mm_bf16<1><<<mmgrid, 256, 0, stream>>>(tb, T3, T2, T4, U, T2,
        tb, T3, nullptr, nullptr, 1, 1, 2.0f, -1.0f, 0.0f,
        (float)a[5], (float)a[6], (float)a[7], (float)a[8],
        (float)(a[0] - a[8]), (float)(a[1] - a[7]), (float)(a[2] - a[6]),
        (float)(a[3] - a[5]), (float)a[4]);
    // feats = 2 T4@U + C0  (bf16 into tb) + fused out partials
    mm_bf16<2><<<mmgrid, 256, 0, stream>>>(T4, U, T2, tb, nullptr, nullptr,
        nullptr, nullptr, Wsb, outpart, 1, 1, 2.0f, 1.0f, 0.0f,
        0,0,0,0, 0,0,0,0,0);
    u16* feats = tb;

    out_reduce_kernel<<<5, 256, 0, stream>>>(outpart, out);

    cpart_kernel<<<dim3(32, 8), 256, 0, stream>>>(feats, cpart);
    cfinal_kernel<<<32, 256, 0, stream>>>(cpart, centerb);

    // P[c] = Ws_bf16[c] @ center  (fp32 out)
    mm_bf16<3><<<dim3(2, 2, CDIM), 256, 0, stream>>>(Wsb, centerb, nullptr, P,
        nullptr, nullptr, nullptr, nullptr, nullptr, nullptr, 0, 0, 1.0f, 0.0f, 0.0f,
        0,0,0,0, 0,0,0,0,0);
    g_kernel<<<dim3(CDIM, 8), 256, 0, stream>>>(P, gpart);
    gmean_kernel<<<1, 64, 0, stream>>>(gpart, out);
}